// Round 15
// baseline (288.466 us; speedup 1.0000x reference)
//
#include <hip/hip_runtime.h>

// CasualSelfAttention fused block for MI355X (gfx950).
// B=4, T=2048, C=1024, H=16, D=64.
// x->bf16 conv -> weight transpose+conv -> 2-phase dbuf 128x128 QKV GEMM (DMA staging,
// Q pre-scaled, V written transposed) -> flash v8 (4 waves x 32q, KVBLK=64, 1024 blocks,
// 4 blocks/CU = 4 waves/SIMD, balanced resident-set qt permutation) -> proj GEMM.
// Workspace (75,497,472 B):
//   [0,        33554432)  qk  bf16 [B,T,2C]      (Q cols 0..1023 pre-scaled, K cols 1024..2047)
//   [33554432, 50331648)  vT  bf16 [B*H][64][T]
//   [50331648, 67108864)  xbf bf16 [B,T,C] (QKV phase) / attn bf16 [B,T,C] (flash+proj phase)
//   [67108864, 73400320)  w_attn^T bf16 [3C][C]
//   [73400320, 75497472)  w_proj^T bf16 [C][C]

using u16 = unsigned short;
using u32 = unsigned int;
using bf16x8 = __attribute__((ext_vector_type(8))) __bf16;
using f32x4  = __attribute__((ext_vector_type(4))) float;
using f32x16 = __attribute__((ext_vector_type(16))) float;
using u16x8  = __attribute__((ext_vector_type(8))) u16;
using u16x4  = __attribute__((ext_vector_type(4))) u16;
using u32x2  = __attribute__((ext_vector_type(2))) u32;
using u32x4  = __attribute__((ext_vector_type(4))) u32;
using fvec4  = __attribute__((ext_vector_type(4))) float;

__device__ __forceinline__ u16 f2bf(float f) {
  u32 u = __builtin_bit_cast(u32, f);
  u32 r = (u + 0x7FFFu + ((u >> 16) & 1u)) >> 16;
  return (u16)r;
}

__device__ __forceinline__ u32 cvtpk(float lo, float hi) {
  u32 r;
  asm("v_cvt_pk_bf16_f32 %0, %1, %2" : "=v"(r) : "v"(lo), "v"(hi));
  return r;
}

__device__ __forceinline__ f32x4 mfma16(bf16x8 a, bf16x8 b, f32x4 c) {
  return __builtin_amdgcn_mfma_f32_16x16x32_bf16(a, b, c, 0, 0, 0);
}

__device__ __forceinline__ f32x16 mfma32(bf16x8 a, bf16x8 b, f32x16 c) {
  return __builtin_amdgcn_mfma_f32_32x32x16_bf16(a, b, c, 0, 0, 0);
}

__device__ __forceinline__ void gld16(const u16* g, u16* l) {
  __builtin_amdgcn_global_load_lds(
      (const __attribute__((address_space(1))) void*)g,
      (__attribute__((address_space(3))) void*)l, 16, 0, 0);
}

// ---------------- f32 -> bf16 bulk convert ----------------
__global__ __launch_bounds__(256) void conv_kernel(
    const float* __restrict__ in, u16* __restrict__ out) {
  const size_t i = ((size_t)blockIdx.x * 256 + threadIdx.x) * 8;
  fvec4 a = *(const fvec4*)(in + i);
  fvec4 b = *(const fvec4*)(in + i + 4);
  u16x8 h;
#pragma unroll
  for (int j = 0; j < 4; ++j) { h[j] = f2bf(a[j]); h[4 + j] = f2bf(b[j]); }
  *(u16x8*)(out + i) = h;
}

// ---------------- transpose + f32->bf16 convert: W[K][N] -> Wt[N][K] ----------------
__global__ __launch_bounds__(256) void transpose_conv_kernel(
    const float* __restrict__ W, u16* __restrict__ Wt, int K, int N) {
  __shared__ float tile[32][33];
  const int n0 = blockIdx.x * 32, k0 = blockIdx.y * 32;
  const int tx = threadIdx.x, ty = threadIdx.y;  // 32 x 8
#pragma unroll
  for (int j = 0; j < 4; ++j)
    tile[ty + j * 8][tx] = W[(size_t)(k0 + ty + j * 8) * N + n0 + tx];
  __syncthreads();
#pragma unroll
  for (int j = 0; j < 4; ++j)
    Wt[(size_t)(n0 + ty + j * 8) * K + k0 + tx] = f2bf(tile[tx][ty + j * 8]);
}

// ---------------- 128x128x32 2-phase dbuf bf16 GEMM (round-8/12 proven) ----------------
template <bool QKV>
__global__ __launch_bounds__(256) void gemm_kernel(
    const u16* __restrict__ A, const u16* __restrict__ Bt,
    const float* __restrict__ bias, void* __restrict__ Cp,
    u16* __restrict__ vt, int M, int N, int K) {
  constexpr float SC = 0.18033688011112042f;  // 0.125 * log2(e)
  __shared__ u16 As[2][4096];
  __shared__ u16 Bs[2][4096];
  const int tid = threadIdx.x;
  const int l = tid & 63, w = tid >> 6;
  const int l15 = l & 15, l16 = l >> 4;
  const int wm = (w >> 1) * 64, wn = (w & 1) * 64;

  const u32 nwg = gridDim.x * gridDim.y;
  u32 f = blockIdx.y * gridDim.x + blockIdx.x;
  f = (f & 7) * (nwg >> 3) + (f >> 3);
  const long mbase = (long)(f / gridDim.x) * 128;
  const long nbase = (long)(f % gridDim.x) * 128;

  const int srow = tid >> 2;
  const int scol = ((tid & 3) ^ ((srow >> 1) & 3)) * 8;
  const u16* gA0 = A + (mbase + srow) * (long)K + scol;
  const u16* gA1 = gA0 + 64 * (long)K;
  const u16* gB0 = Bt + (nbase + srow) * (long)K + scol;
  const u16* gB1 = gB0 + 64 * (long)K;

  f32x4 acc[4][4] = {};
  const int NT = K >> 5;

#define STAGE(buf, koff)                         \
  gld16(gA0 + (koff), &As[buf][tid * 8]);        \
  gld16(gA1 + (koff), &As[buf][tid * 8 + 2048]); \
  gld16(gB0 + (koff), &Bs[buf][tid * 8]);        \
  gld16(gB1 + (koff), &Bs[buf][tid * 8 + 2048]);

  STAGE(0, 0);
  asm volatile("s_waitcnt vmcnt(0)" ::: "memory");
  __builtin_amdgcn_s_barrier();

  for (int t = 0; t < NT; ++t) {
    const int cur = t & 1;
    if (t + 1 < NT) { STAGE(cur ^ 1, (t + 1) * 32); }

    bf16x8 af[4], bfr[4];
#pragma unroll
    for (int i = 0; i < 4; ++i) {
      const int row = wm + i * 16 + l15;
      af[i] = *(const bf16x8*)(&As[cur][row * 32 + ((l16 ^ ((row >> 1) & 3)) * 8)]);
    }
#pragma unroll
    for (int j = 0; j < 4; ++j) {
      const int row = wn + j * 16 + l15;
      bfr[j] = *(const bf16x8*)(&Bs[cur][row * 32 + ((l16 ^ ((row >> 1) & 3)) * 8)]);
    }
    asm volatile("s_waitcnt lgkmcnt(0)" ::: "memory");
    __builtin_amdgcn_sched_barrier(0);
    __builtin_amdgcn_s_setprio(1);
#pragma unroll
    for (int i = 0; i < 4; ++i)
#pragma unroll
      for (int j = 0; j < 4; ++j)
        acc[i][j] = mfma16(af[i], bfr[j], acc[i][j]);
    __builtin_amdgcn_s_setprio(0);
    __builtin_amdgcn_sched_barrier(0);
    if (t + 1 < NT) { asm volatile("s_waitcnt vmcnt(0)" ::: "memory"); }
    __builtin_amdgcn_s_barrier();
  }
#undef STAGE

  if constexpr (QKV) {
    const bool isv = (nbase >= 2048);
#pragma unroll
    for (int i = 0; i < 4; ++i) {
#pragma unroll
      for (int j = 0; j < 4; ++j) {
        const long m0 = mbase + wm + i * 16 + l16 * 4;
        const int n = (int)nbase + wn + j * 16 + l15;
        const float bv = bias[n];
        if (!isv) {
          u16* qkp = (u16*)Cp;
          const float sc = (n < 1024) ? SC : 1.0f;
#pragma unroll
          for (int r = 0; r < 4; ++r)
            qkp[(m0 + r) * 2048 + n] = f2bf((acc[i][j][r] + bv) * sc);
        } else {
          const int vc = n - 2048, hh = vc >> 6, dd = vc & 63;
          const int bb = (int)(m0 >> 11), t0 = (int)(m0 & 2047);
          u16x4 pk;
#pragma unroll
          for (int r = 0; r < 4; ++r) pk[r] = f2bf(acc[i][j][r] + bv);
          *(u16x4*)(vt + ((size_t)(bb * 16 + hh) * 64 + dd) * 2048 + t0) = pk;
        }
      }
    }
  } else {
#pragma unroll
    for (int i = 0; i < 4; ++i) {
#pragma unroll
      for (int j = 0; j < 4; ++j) {
        const long row0 = mbase + wm + i * 16 + l16 * 4;
        const long col = nbase + wn + j * 16 + l15;
        const float bv = bias[col];
#pragma unroll
        for (int r = 0; r < 4; ++r)
          ((float*)Cp)[(row0 + r) * (long)N + col] = acc[i][j][r] + bv;
      }
    }
  }
}

// ---------------- flash v8: unpaired grid, 4 blocks/CU = 4 waves/SIMD ----------------
// grid 1024 = 16 qt-slots x 64 bh; block = 256 thr = 4 waves x 32 q (QBLK=128).
// Balanced resident sets: CU c hosts slots {x,x+4,x+8,x+12}; slot->qt map
// {15-j, j, 11-j, 4+j} makes every CU's qt-sum = 30 (equal work per CU).
// bh = i&63 -> i==bh (mod 8): all 16 blocks of a (b,h) on one XCD (L2 reuse).
// KVBLK=64 dbuf (32 KB LDS -> 4 blocks/CU). K,V staged via global_load_lds DMA
// (pre-swizzled source, linear dest); one vmcnt(0)+barrier per iter.
// Per-32-key wave-uniform causal skip on QK, exp2 AND PV.
// Softmax p = exp2(s) (fixed shift cancels exactly in normalization).
__global__ __launch_bounds__(256, 4) void flash_kernel(
    const u16* __restrict__ qk, const u16* __restrict__ vt, u16* __restrict__ attn_out) {
  __shared__ u16 Ks[2][64 * 64];  // [buf][key][64 d], slot^=(row&7) swizzle
  __shared__ u16 Vs[2][64 * 64];  // [buf][d][64 key]
  const int tid = threadIdx.x;
  const int lane = tid & 63, w = tid >> 6;
  const int l31 = lane & 31, hi = lane >> 5;
  const int xorv = (l31 & 7) << 4;

  const int i = blockIdx.x;
  const int bh = i & 63;
  const int s = i >> 6;  // 0..15
  const int g = s >> 2, j = s & 3;
  const int qt = (g == 0) ? (15 - j) : (g == 1) ? j : (g == 2) ? (11 - j) : (4 + j);
  const int b = bh >> 4, h = bh & 15;
  const u16* qbase = qk + (size_t)b * 2048 * 2048 + h * 64;
  const u16* kbase = qbase + 1024;
  const u16* vbase = vt + (size_t)bh * 64 * 2048;
  u16* obase = attn_out + (size_t)b * 2048 * 1024 + h * 64;

  // DMA staging: thread covers rows sr, sr+32 per 64-row tile; 16B slot pre-swizzled
  const int sr = tid >> 3;
  const int ss = (tid & 7) ^ (sr & 7);
  const u16* gk = kbase + (size_t)sr * 2048 + ss * 8;
  const u16* gv = vbase + (size_t)sr * 2048 + ss * 8;

  const int nt = 2 * qt + 2;
  const int qr0 = qt * 128 + w * 32;
  const int q = qr0 + l31;
  const int qmax = qr0 + 31;

  // Q B-frags: col=q, k(d) = ds*16 + hi*8 + e
  bf16x8 qf[4];
#pragma unroll
  for (int ds = 0; ds < 4; ++ds)
    qf[ds] = *(const bf16x8*)(qbase + (size_t)q * 2048 + ds * 16 + hi * 8);

  f32x16 oacc[2] = {};
  float lsum = 0.f;

  // prologue: DMA K,V tile 0 into buf 0
  gld16(gk, &Ks[0][tid * 8]);
  gld16(gk + (size_t)32 * 2048, &Ks[0][tid * 8 + 2048]);
  gld16(gv, &Vs[0][tid * 8]);
  gld16(gv + (size_t)32 * 2048, &Vs[0][tid * 8 + 2048]);
  asm volatile("s_waitcnt vmcnt(0)" ::: "memory");
  __builtin_amdgcn_s_barrier();

  int cur = 0;
  for (int kt = 0; kt < nt; ++kt) {
    const int kb = kt * 64;
    if (kt + 1 < nt) {  // DMA next tile into other buffer; lands under compute
      gld16(gk + (size_t)(kb + 64) * 2048, &Ks[cur ^ 1][tid * 8]);
      gld16(gk + (size_t)(kb + 96) * 2048, &Ks[cur ^ 1][tid * 8 + 2048]);
      gld16(gv + (size_t)(kb + 64), &Vs[cur ^ 1][tid * 8]);
      gld16(gv + (size_t)32 * 2048 + (kb + 64), &Vs[cur ^ 1][tid * 8 + 2048]);
    }

    bf16x8 pf[4];
#pragma unroll
    for (int kh = 0; kh < 2; ++kh) {
      const int kb32 = kb + kh * 32;
      if (kb32 <= qmax) {  // wave-uniform causal 32-key block skip
        f32x16 sacc = {};
        __builtin_amdgcn_s_setprio(1);
#pragma unroll
        for (int ds = 0; ds < 4; ++ds) {
          const int col = (ds * 32 + hi * 16) ^ xorv;
          bf16x8 kf = *(const bf16x8*)((const char*)&Ks[cur][0] + (kh * 32 + l31) * 128 + col);
          sacc = mfma32(kf, qf[ds], sacc);
        }
        __builtin_amdgcn_s_setprio(0);

        if (kb32 + 31 > qr0) {  // boundary block: per-element mask
#pragma unroll
          for (int r = 0; r < 16; ++r) {
            const int key = kb32 + (r & 3) + 8 * (r >> 2) + 4 * hi;
            if (key > q) sacc[r] = -1e30f;
          }
        }

        float ps = 0.f;
#pragma unroll
        for (int r = 0; r < 16; ++r) { sacc[r] = exp2f(sacc[r]); ps += sacc[r]; }
        lsum += ps;

#pragma unroll
        for (int c = 0; c < 2; ++c) {
          const int bs = c * 8;
          u32 L0 = cvtpk(sacc[bs + 0], sacc[bs + 1]);
          u32 L1 = cvtpk(sacc[bs + 2], sacc[bs + 3]);
          u32 L2 = cvtpk(sacc[bs + 4], sacc[bs + 5]);
          u32 L3 = cvtpk(sacc[bs + 6], sacc[bs + 7]);
          asm("v_permlane32_swap_b32 %0, %1" : "+v"(L0), "+v"(L2));
          asm("v_permlane32_swap_b32 %0, %1" : "+v"(L1), "+v"(L3));
          u32x4 pk = {L0, L1, L2, L3};
          pf[kh * 2 + c] = __builtin_bit_cast(bf16x8, pk);
        }
      }
    }

    // O^T += V^T P (skip PV for skipped key-blocks)
    __builtin_amdgcn_s_setprio(1);
#pragma unroll
    for (int dh = 0; dh < 2; ++dh)
#pragma unroll
      for (int ks = 0; ks < 4; ++ks) {
        if (kb + (ks >> 1) * 32 <= qmax) {
          const int col = (ks * 32 + hi * 16) ^ xorv;
          bf16x8 vf = *(const bf16x8*)((const char*)&Vs[cur][0] + (dh * 32 + l31) * 128 + col);
          oacc[dh] = mfma32(vf, pf[ks], oacc[dh]);
        }
      }
    __builtin_amdgcn_s_setprio(0);

    asm volatile("s_waitcnt vmcnt(0)" ::: "memory");  // next-tile DMAs resident
    __builtin_amdgcn_s_barrier();                     // all waves done with buf[cur]
    cur ^= 1;
  }

  // epilogue: full row-sum (partner lane holds other 32 keys), normalize, packed store
  lsum += __shfl_xor(lsum, 32);
  const float inv = 1.0f / lsum;
  u16* orow = obase + (size_t)q * 1024;
#pragma unroll
  for (int dh = 0; dh < 2; ++dh) {
#pragma unroll
    for (int jq = 0; jq < 4; ++jq) {
      u32x2 pk;
      pk[0] = cvtpk(oacc[dh][jq * 4 + 0] * inv, oacc[dh][jq * 4 + 1] * inv);
      pk[1] = cvtpk(oacc[dh][jq * 4 + 2] * inv, oacc[dh][jq * 4 + 3] * inv);
      *(u32x2*)(orow + dh * 32 + 8 * jq + 4 * hi) = pk;
    }
  }
}

extern "C" void kernel_launch(void* const* d_in, const int* in_sizes, int n_in,
                              void* d_out, int out_size, void* d_ws, size_t ws_size,
                              hipStream_t stream) {
  (void)in_sizes; (void)n_in; (void)out_size; (void)ws_size;
  const float* x      = (const float*)d_in[0];  // [4,2048,1024]
  const float* w_attn = (const float*)d_in[1];  // [1024,3072]
  const float* b_attn = (const float*)d_in[2];  // [3072]
  const float* w_proj = (const float*)d_in[3];  // [1024,1024]
  const float* b_proj = (const float*)d_in[4];  // [1024]
  float* out = (float*)d_out;                   // [4,2048,1024] f32

  char* ws = (char*)d_ws;
  u16* qkbuf = (u16*)(ws);                   // 33,554,432 B
  u16* vtbuf = (u16*)(ws + 33554432);        // 16,777,216 B
  u16* xbf   = (u16*)(ws + 50331648);        // 16,777,216 B (reused as attn after QKV)
  u16* attnb = (u16*)(ws + 50331648);
  u16* wtA   = (u16*)(ws + 67108864);        //  6,291,456 B
  u16* wtP   = (u16*)(ws + 73400320);        //  2,097,152 B

  conv_kernel<<<4096, 256, 0, stream>>>(x, xbf);
  transpose_conv_kernel<<<dim3(3072 / 32, 1024 / 32), dim3(32, 8), 0, stream>>>(w_attn, wtA, 1024, 3072);
  transpose_conv_kernel<<<dim3(1024 / 32, 1024 / 32), dim3(32, 8), 0, stream>>>(w_proj, wtP, 1024, 1024);

  // QKV GEMM: xbf[8192,1024] @ w_attn^T -> qk (Q pre-scaled) + vT
  gemm_kernel<true><<<dim3(3072 / 128, 8192 / 128), 256, 0, stream>>>(
      xbf, wtA, b_attn, qkbuf, vtbuf, 8192, 3072, 1024);

  // flash attention (1024 blocks, balanced resident sets, 4 blocks/CU)
  flash_kernel<<<1024, 256, 0, stream>>>(qkbuf, vtbuf, attnb);

  // output projection
  gemm_kernel<false><<<dim3(1024 / 128, 8192 / 128), 256, 0, stream>>>(
      attnb, wtP, b_proj, out, nullptr, 8192, 1024, 1024);
}

// Round 16
// 240.003 us; speedup vs baseline: 1.2019x; 1.2019x over previous
//
#include <hip/hip_runtime.h>

// CasualSelfAttention fused block for MI355X (gfx950).
// B=4, T=2048, C=1024, H=16, D=64.
// x->bf16 conv -> weight transpose+conv -> 2-phase dbuf 128x128 QKV GEMM (DMA staging,
// Q pre-scaled, V written transposed) -> flash v9 (4 waves x 32q, KVBLK=64, 1024 blocks,
// NO vgpr cap; balanced-in-both-regimes qt permutation) -> proj GEMM.
// Workspace (75,497,472 B):
//   [0,        33554432)  qk  bf16 [B,T,2C]      (Q cols 0..1023 pre-scaled, K cols 1024..2047)
//   [33554432, 50331648)  vT  bf16 [B*H][64][T]
//   [50331648, 67108864)  xbf bf16 [B,T,C] (QKV phase) / attn bf16 [B,T,C] (flash+proj phase)
//   [67108864, 73400320)  w_attn^T bf16 [3C][C]
//   [73400320, 75497472)  w_proj^T bf16 [C][C]

using u16 = unsigned short;
using u32 = unsigned int;
using bf16x8 = __attribute__((ext_vector_type(8))) __bf16;
using f32x4  = __attribute__((ext_vector_type(4))) float;
using f32x16 = __attribute__((ext_vector_type(16))) float;
using u16x8  = __attribute__((ext_vector_type(8))) u16;
using u16x4  = __attribute__((ext_vector_type(4))) u16;
using u32x2  = __attribute__((ext_vector_type(2))) u32;
using u32x4  = __attribute__((ext_vector_type(4))) u32;
using fvec4  = __attribute__((ext_vector_type(4))) float;

__device__ __forceinline__ u16 f2bf(float f) {
  u32 u = __builtin_bit_cast(u32, f);
  u32 r = (u + 0x7FFFu + ((u >> 16) & 1u)) >> 16;
  return (u16)r;
}

__device__ __forceinline__ u32 cvtpk(float lo, float hi) {
  u32 r;
  asm("v_cvt_pk_bf16_f32 %0, %1, %2" : "=v"(r) : "v"(lo), "v"(hi));
  return r;
}

__device__ __forceinline__ f32x4 mfma16(bf16x8 a, bf16x8 b, f32x4 c) {
  return __builtin_amdgcn_mfma_f32_16x16x32_bf16(a, b, c, 0, 0, 0);
}

__device__ __forceinline__ f32x16 mfma32(bf16x8 a, bf16x8 b, f32x16 c) {
  return __builtin_amdgcn_mfma_f32_32x32x16_bf16(a, b, c, 0, 0, 0);
}

__device__ __forceinline__ void gld16(const u16* g, u16* l) {
  __builtin_amdgcn_global_load_lds(
      (const __attribute__((address_space(1))) void*)g,
      (__attribute__((address_space(3))) void*)l, 16, 0, 0);
}

// ---------------- f32 -> bf16 bulk convert ----------------
__global__ __launch_bounds__(256) void conv_kernel(
    const float* __restrict__ in, u16* __restrict__ out) {
  const size_t i = ((size_t)blockIdx.x * 256 + threadIdx.x) * 8;
  fvec4 a = *(const fvec4*)(in + i);
  fvec4 b = *(const fvec4*)(in + i + 4);
  u16x8 h;
#pragma unroll
  for (int j = 0; j < 4; ++j) { h[j] = f2bf(a[j]); h[4 + j] = f2bf(b[j]); }
  *(u16x8*)(out + i) = h;
}

// ---------------- transpose + f32->bf16 convert: W[K][N] -> Wt[N][K] ----------------
__global__ __launch_bounds__(256) void transpose_conv_kernel(
    const float* __restrict__ W, u16* __restrict__ Wt, int K, int N) {
  __shared__ float tile[32][33];
  const int n0 = blockIdx.x * 32, k0 = blockIdx.y * 32;
  const int tx = threadIdx.x, ty = threadIdx.y;  // 32 x 8
#pragma unroll
  for (int j = 0; j < 4; ++j)
    tile[ty + j * 8][tx] = W[(size_t)(k0 + ty + j * 8) * N + n0 + tx];
  __syncthreads();
#pragma unroll
  for (int j = 0; j < 4; ++j)
    Wt[(size_t)(n0 + ty + j * 8) * K + k0 + tx] = f2bf(tile[tx][ty + j * 8]);
}

// ---------------- 128x128x32 2-phase dbuf bf16 GEMM (round-8/12 proven) ----------------
template <bool QKV>
__global__ __launch_bounds__(256) void gemm_kernel(
    const u16* __restrict__ A, const u16* __restrict__ Bt,
    const float* __restrict__ bias, void* __restrict__ Cp,
    u16* __restrict__ vt, int M, int N, int K) {
  constexpr float SC = 0.18033688011112042f;  // 0.125 * log2(e)
  __shared__ u16 As[2][4096];
  __shared__ u16 Bs[2][4096];
  const int tid = threadIdx.x;
  const int l = tid & 63, w = tid >> 6;
  const int l15 = l & 15, l16 = l >> 4;
  const int wm = (w >> 1) * 64, wn = (w & 1) * 64;

  const u32 nwg = gridDim.x * gridDim.y;
  u32 f = blockIdx.y * gridDim.x + blockIdx.x;
  f = (f & 7) * (nwg >> 3) + (f >> 3);
  const long mbase = (long)(f / gridDim.x) * 128;
  const long nbase = (long)(f % gridDim.x) * 128;

  const int srow = tid >> 2;
  const int scol = ((tid & 3) ^ ((srow >> 1) & 3)) * 8;
  const u16* gA0 = A + (mbase + srow) * (long)K + scol;
  const u16* gA1 = gA0 + 64 * (long)K;
  const u16* gB0 = Bt + (nbase + srow) * (long)K + scol;
  const u16* gB1 = gB0 + 64 * (long)K;

  f32x4 acc[4][4] = {};
  const int NT = K >> 5;

#define STAGE(buf, koff)                         \
  gld16(gA0 + (koff), &As[buf][tid * 8]);        \
  gld16(gA1 + (koff), &As[buf][tid * 8 + 2048]); \
  gld16(gB0 + (koff), &Bs[buf][tid * 8]);        \
  gld16(gB1 + (koff), &Bs[buf][tid * 8 + 2048]);

  STAGE(0, 0);
  asm volatile("s_waitcnt vmcnt(0)" ::: "memory");
  __builtin_amdgcn_s_barrier();

  for (int t = 0; t < NT; ++t) {
    const int cur = t & 1;
    if (t + 1 < NT) { STAGE(cur ^ 1, (t + 1) * 32); }

    bf16x8 af[4], bfr[4];
#pragma unroll
    for (int i = 0; i < 4; ++i) {
      const int row = wm + i * 16 + l15;
      af[i] = *(const bf16x8*)(&As[cur][row * 32 + ((l16 ^ ((row >> 1) & 3)) * 8)]);
    }
#pragma unroll
    for (int j = 0; j < 4; ++j) {
      const int row = wn + j * 16 + l15;
      bfr[j] = *(const bf16x8*)(&Bs[cur][row * 32 + ((l16 ^ ((row >> 1) & 3)) * 8)]);
    }
    asm volatile("s_waitcnt lgkmcnt(0)" ::: "memory");
    __builtin_amdgcn_sched_barrier(0);
    __builtin_amdgcn_s_setprio(1);
#pragma unroll
    for (int i = 0; i < 4; ++i)
#pragma unroll
      for (int j = 0; j < 4; ++j)
        acc[i][j] = mfma16(af[i], bfr[j], acc[i][j]);
    __builtin_amdgcn_s_setprio(0);
    __builtin_amdgcn_sched_barrier(0);
    if (t + 1 < NT) { asm volatile("s_waitcnt vmcnt(0)" ::: "memory"); }
    __builtin_amdgcn_s_barrier();
  }
#undef STAGE

  if constexpr (QKV) {
    const bool isv = (nbase >= 2048);
#pragma unroll
    for (int i = 0; i < 4; ++i) {
#pragma unroll
      for (int j = 0; j < 4; ++j) {
        const long m0 = mbase + wm + i * 16 + l16 * 4;
        const int n = (int)nbase + wn + j * 16 + l15;
        const float bv = bias[n];
        if (!isv) {
          u16* qkp = (u16*)Cp;
          const float sc = (n < 1024) ? SC : 1.0f;
#pragma unroll
          for (int r = 0; r < 4; ++r)
            qkp[(m0 + r) * 2048 + n] = f2bf((acc[i][j][r] + bv) * sc);
        } else {
          const int vc = n - 2048, hh = vc >> 6, dd = vc & 63;
          const int bb = (int)(m0 >> 11), t0 = (int)(m0 & 2047);
          u16x4 pk;
#pragma unroll
          for (int r = 0; r < 4; ++r) pk[r] = f2bf(acc[i][j][r] + bv);
          *(u16x4*)(vt + ((size_t)(bb * 16 + hh) * 64 + dd) * 2048 + t0) = pk;
        }
      }
    }
  } else {
#pragma unroll
    for (int i = 0; i < 4; ++i) {
#pragma unroll
      for (int j = 0; j < 4; ++j) {
        const long row0 = mbase + wm + i * 16 + l16 * 4;
        const long col = nbase + wn + j * 16 + l15;
        const float bv = bias[col];
#pragma unroll
        for (int r = 0; r < 4; ++r)
          ((float*)Cp)[(row0 + r) * (long)N + col] = acc[i][j][r] + bv;
      }
    }
  }
}

// ---------------- flash v9: v8 grid/body, NO vgpr cap ----------------
// grid 1024 = 16 qt-slots x 64 bh; block = 256 thr = 4 waves x 32 q (QBLK=128).
// slot->qt map {15-j, j, 11-j, 4+j}: balanced for BOTH 4-resident sets
// ({x,x+4,x+8,x+12} sum 30) and 2-resident sets ({x,x+4}/{x+8,x+12} sum 15).
// bh = i&63 -> i==bh (mod 8): all 16 blocks of a (b,h) on one XCD.
// KVBLK=64 dbuf (32 KB LDS). K,V via global_load_lds DMA (pre-swizzled source);
// one vmcnt(0)+barrier per iter. Per-32-key wave-uniform causal skip.
// Softmax p = exp2(s) (fixed shift cancels exactly in normalization).
// launch_bounds(256) ONLY: r15's (256,4) capped VGPR at 64 -> scratch spills
// (WRITE_SIZE 16->44 MB, MfmaUtil 7%). Let allocator pick ~110; <=128 gives
// 4 blocks/CU at runtime, >128 falls back to 2 blocks/CU (= r14 perf).
__global__ __launch_bounds__(256) void flash_kernel(
    const u16* __restrict__ qk, const u16* __restrict__ vt, u16* __restrict__ attn_out) {
  __shared__ u16 Ks[2][64 * 64];  // [buf][key][64 d], slot^=(row&7) swizzle
  __shared__ u16 Vs[2][64 * 64];  // [buf][d][64 key]
  const int tid = threadIdx.x;
  const int lane = tid & 63, w = tid >> 6;
  const int l31 = lane & 31, hi = lane >> 5;
  const int xorv = (l31 & 7) << 4;

  const int i = blockIdx.x;
  const int bh = i & 63;
  const int s = i >> 6;  // 0..15
  const int g = s >> 2, j = s & 3;
  const int qt = (g == 0) ? (15 - j) : (g == 1) ? j : (g == 2) ? (11 - j) : (4 + j);
  const int b = bh >> 4, h = bh & 15;
  const u16* qbase = qk + (size_t)b * 2048 * 2048 + h * 64;
  const u16* kbase = qbase + 1024;
  const u16* vbase = vt + (size_t)bh * 64 * 2048;
  u16* obase = attn_out + (size_t)b * 2048 * 1024 + h * 64;

  // DMA staging: thread covers rows sr, sr+32 per 64-row tile; 16B slot pre-swizzled
  const int sr = tid >> 3;
  const int ss = (tid & 7) ^ (sr & 7);
  const u16* gk = kbase + (size_t)sr * 2048 + ss * 8;
  const u16* gv = vbase + (size_t)sr * 2048 + ss * 8;

  const int nt = 2 * qt + 2;
  const int qr0 = qt * 128 + w * 32;
  const int q = qr0 + l31;
  const int qmax = qr0 + 31;

  // Q B-frags: col=q, k(d) = ds*16 + hi*8 + e
  bf16x8 qf[4];
#pragma unroll
  for (int ds = 0; ds < 4; ++ds)
    qf[ds] = *(const bf16x8*)(qbase + (size_t)q * 2048 + ds * 16 + hi * 8);

  f32x16 oacc[2] = {};
  float lsum = 0.f;

  // prologue: DMA K,V tile 0 into buf 0
  gld16(gk, &Ks[0][tid * 8]);
  gld16(gk + (size_t)32 * 2048, &Ks[0][tid * 8 + 2048]);
  gld16(gv, &Vs[0][tid * 8]);
  gld16(gv + (size_t)32 * 2048, &Vs[0][tid * 8 + 2048]);
  asm volatile("s_waitcnt vmcnt(0)" ::: "memory");
  __builtin_amdgcn_s_barrier();

  int cur = 0;
  for (int kt = 0; kt < nt; ++kt) {
    const int kb = kt * 64;
    if (kt + 1 < nt) {  // DMA next tile into other buffer; lands under compute
      gld16(gk + (size_t)(kb + 64) * 2048, &Ks[cur ^ 1][tid * 8]);
      gld16(gk + (size_t)(kb + 96) * 2048, &Ks[cur ^ 1][tid * 8 + 2048]);
      gld16(gv + (size_t)(kb + 64), &Vs[cur ^ 1][tid * 8]);
      gld16(gv + (size_t)32 * 2048 + (kb + 64), &Vs[cur ^ 1][tid * 8 + 2048]);
    }

    bf16x8 pf[4];
#pragma unroll
    for (int kh = 0; kh < 2; ++kh) {
      const int kb32 = kb + kh * 32;
      if (kb32 <= qmax) {  // wave-uniform causal 32-key block skip
        f32x16 sacc = {};
        __builtin_amdgcn_s_setprio(1);
#pragma unroll
        for (int ds = 0; ds < 4; ++ds) {
          const int col = (ds * 32 + hi * 16) ^ xorv;
          bf16x8 kf = *(const bf16x8*)((const char*)&Ks[cur][0] + (kh * 32 + l31) * 128 + col);
          sacc = mfma32(kf, qf[ds], sacc);
        }
        __builtin_amdgcn_s_setprio(0);

        if (kb32 + 31 > qr0) {  // boundary block: per-element mask
#pragma unroll
          for (int r = 0; r < 16; ++r) {
            const int key = kb32 + (r & 3) + 8 * (r >> 2) + 4 * hi;
            if (key > q) sacc[r] = -1e30f;
          }
        }

        float ps = 0.f;
#pragma unroll
        for (int r = 0; r < 16; ++r) { sacc[r] = exp2f(sacc[r]); ps += sacc[r]; }
        lsum += ps;

#pragma unroll
        for (int c = 0; c < 2; ++c) {
          const int bs = c * 8;
          u32 L0 = cvtpk(sacc[bs + 0], sacc[bs + 1]);
          u32 L1 = cvtpk(sacc[bs + 2], sacc[bs + 3]);
          u32 L2 = cvtpk(sacc[bs + 4], sacc[bs + 5]);
          u32 L3 = cvtpk(sacc[bs + 6], sacc[bs + 7]);
          asm("v_permlane32_swap_b32 %0, %1" : "+v"(L0), "+v"(L2));
          asm("v_permlane32_swap_b32 %0, %1" : "+v"(L1), "+v"(L3));
          u32x4 pk = {L0, L1, L2, L3};
          pf[kh * 2 + c] = __builtin_bit_cast(bf16x8, pk);
        }
      }
    }

    // O^T += V^T P (skip PV for skipped key-blocks)
    __builtin_amdgcn_s_setprio(1);
#pragma unroll
    for (int dh = 0; dh < 2; ++dh)
#pragma unroll
      for (int ks = 0; ks < 4; ++ks) {
        if (kb + (ks >> 1) * 32 <= qmax) {
          const int col = (ks * 32 + hi * 16) ^ xorv;
          bf16x8 vf = *(const bf16x8*)((const char*)&Vs[cur][0] + (dh * 32 + l31) * 128 + col);
          oacc[dh] = mfma32(vf, pf[ks], oacc[dh]);
        }
      }
    __builtin_amdgcn_s_setprio(0);

    asm volatile("s_waitcnt vmcnt(0)" ::: "memory");  // next-tile DMAs resident
    __builtin_amdgcn_s_barrier();                     // all waves done with buf[cur]
    cur ^= 1;
  }

  // epilogue: full row-sum (partner lane holds other 32 keys), normalize, packed store
  lsum += __shfl_xor(lsum, 32);
  const float inv = 1.0f / lsum;
  u16* orow = obase + (size_t)q * 1024;
#pragma unroll
  for (int dh = 0; dh < 2; ++dh) {
#pragma unroll
    for (int jq = 0; jq < 4; ++jq) {
      u32x2 pk;
      pk[0] = cvtpk(oacc[dh][jq * 4 + 0] * inv, oacc[dh][jq * 4 + 1] * inv);
      pk[1] = cvtpk(oacc[dh][jq * 4 + 2] * inv, oacc[dh][jq * 4 + 3] * inv);
      *(u32x2*)(orow + dh * 32 + 8 * jq + 4 * hi) = pk;
    }
  }
}

extern "C" void kernel_launch(void* const* d_in, const int* in_sizes, int n_in,
                              void* d_out, int out_size, void* d_ws, size_t ws_size,
                              hipStream_t stream) {
  (void)in_sizes; (void)n_in; (void)out_size; (void)ws_size;
  const float* x      = (const float*)d_in[0];  // [4,2048,1024]
  const float* w_attn = (const float*)d_in[1];  // [1024,3072]
  const float* b_attn = (const float*)d_in[2];  // [3072]
  const float* w_proj = (const float*)d_in[3];  // [1024,1024]
  const float* b_proj = (const float*)d_in[4];  // [1024]
  float* out = (float*)d_out;                   // [4,2048,1024] f32

  char* ws = (char*)d_ws;
  u16* qkbuf = (u16*)(ws);                   // 33,554,432 B
  u16* vtbuf = (u16*)(ws + 33554432);        // 16,777,216 B
  u16* xbf   = (u16*)(ws + 50331648);        // 16,777,216 B (reused as attn after QKV)
  u16* attnb = (u16*)(ws + 50331648);
  u16* wtA   = (u16*)(ws + 67108864);        //  6,291,456 B
  u16* wtP   = (u16*)(ws + 73400320);        //  2,097,152 B

  conv_kernel<<<4096, 256, 0, stream>>>(x, xbf);
  transpose_conv_kernel<<<dim3(3072 / 32, 1024 / 32), dim3(32, 8), 0, stream>>>(w_attn, wtA, 1024, 3072);
  transpose_conv_kernel<<<dim3(1024 / 32, 1024 / 32), dim3(32, 8), 0, stream>>>(w_proj, wtP, 1024, 1024);

  // QKV GEMM: xbf[8192,1024] @ w_attn^T -> qk (Q pre-scaled) + vT
  gemm_kernel<true><<<dim3(3072 / 128, 8192 / 128), 256, 0, stream>>>(
      xbf, wtA, b_attn, qkbuf, vtbuf, 8192, 3072, 1024);

  // flash attention (1024 blocks, balanced permutation, no vgpr cap)
  flash_kernel<<<1024, 256, 0, stream>>>(qkbuf, vtbuf, attnb);

  // output projection
  gemm_kernel<false><<<dim3(1024 / 128, 8192 / 128), 256, 0, stream>>>(
      attnb, wtP, b_proj, out, nullptr, 8192, 1024, 1024);
}